// Round 1
// baseline (369.788 us; speedup 1.0000x reference)
//
#include <hip/hip_runtime.h>
#include <cstdint>
#include <cstddef>

#define NPTS 4096
#define BATCH 4
#define FEAT 256
#define KNN 32

// ---------------- workspace layout (bytes) ----------------
static constexpr size_t OFF_IDX  = 0;                          // int32 [B*N*K]  = 2 MB
static constexpr size_t OFF_HT   = 2u * 1024 * 1024;           // f32  [B*N*F]  = 16 MB
static constexpr size_t OFF_CNT  = OFF_HT + 16u * 1024 * 1024; // int32 [B*N]   = 64 KB
static constexpr size_t OFF_PART = OFF_CNT + 64u * 1024;       // f32  [64*512] = 128 KB
static constexpr size_t OFF_SC   = OFF_PART + 128u * 1024;     // f32 [256]
static constexpr size_t OFF_SH   = OFF_SC + 4096;              // f32 [256]

static __device__ __forceinline__ unsigned long long umin64(unsigned long long a,
                                                            unsigned long long b) {
    return a < b ? a : b;
}

// ---------------- KNN: one wave (64 threads) per (b, n) row ----------------
__global__ __launch_bounds__(64) void knn_kernel(const float* __restrict__ xyz,
                                                 int* __restrict__ out_idx) {
#pragma clang fp contract(off)
    __shared__ uint32_t dist[NPTS];  // layout: [owner_lane][(i + lane) & 63]
    const int n = blockIdx.x;
    const int b = blockIdx.y;
    const int lane = threadIdx.x;
    const float* xb = xyz + (size_t)b * 3 * NPTS;
    const float x0n = xb[n];
    const float x1n = xb[NPTS + n];
    const float sqn = x0n * x0n + x1n * x1n;  // round(x0^2)+round(x1^2), no contraction

    unsigned long long lmin = ~0ull;
    for (int i = 0; i < 64; ++i) {
        const int m = i * 64 + lane;
        const float x0m = xb[m];
        const float x1m = xb[NPTS + m];
        const float sqm = x0m * x0m + x1m * x1m;
        const float p = __builtin_fmaf(x1n, x1m, x0n * x0m);  // fma-accumulated dot
        const float d = (sqm - 2.0f * p) + sqn;               // reference association
        uint32_t u = __float_as_uint(d);
        u = (u & 0x80000000u) ? ~u : (u | 0x80000000u);       // order-preserving map
        dist[lane * 64 + ((i + lane) & 63)] = u;
        lmin = umin64(lmin, ((unsigned long long)u << 32) | (uint32_t)m);
    }
    __syncthreads();

    int* myout = out_idx + ((size_t)b * NPTS + n) * KNN;
    for (int k = 0; k < KNN; ++k) {
        // global min over per-lane mins (butterfly; result in all lanes)
        unsigned long long wkey = lmin;
        for (int off = 1; off < 64; off <<= 1)
            wkey = umin64(wkey, __shfl_xor(wkey, off, 64));
        const uint32_t m_win = (uint32_t)wkey;
        if (lane == 0) myout[k] = (int)m_win;
        const int owner = (int)(m_win & 63u);
        const int i_win = (int)(m_win >> 6);
        if (lane == owner) dist[owner * 64 + ((i_win + owner) & 63)] = 0xFFFFFFFFu;
        __syncthreads();
        // full-wave rescan of owner's row -> owner's new local min
        const uint32_t v = dist[owner * 64 + lane];
        const int i2 = (lane - owner) & 63;
        unsigned long long key2 =
            ((unsigned long long)v << 32) | (uint32_t)(i2 * 64 + owner);
        for (int off = 1; off < 64; off <<= 1)
            key2 = umin64(key2, __shfl_xor(key2, off, 64));
        if (lane == owner) lmin = key2;
        __syncthreads();
    }
}

// ---------------- H = W @ feat[b] + bias, stored as Ht[b][n][f] ----------------
__global__ __launch_bounds__(256) void gemm_kernel(const float* __restrict__ feat,
                                                   const float* __restrict__ W,
                                                   const float* __restrict__ bias,
                                                   float* __restrict__ Ht) {
    __shared__ float As[64][64];  // [c][n_local]
    __shared__ float Bs[64][65];  // [c][f_local], padded
    const int b = blockIdx.z;
    const int n0 = blockIdx.x * 64;
    const int f0 = blockIdx.y * 64;
    const int t = threadIdx.x;
    const int tn = t % 16, tf = t / 16;
    float acc[4][4] = {};
    const float* fb = feat + (size_t)b * FEAT * NPTS;
    for (int c0 = 0; c0 < FEAT; c0 += 64) {
        for (int e = t; e < 4096; e += 256) {
            const int c = e >> 6, nl = e & 63;
            As[c][nl] = fb[(size_t)(c0 + c) * NPTS + n0 + nl];
        }
        for (int e = t; e < 4096; e += 256) {
            const int fl = e >> 6, c = e & 63;
            Bs[c][fl] = W[(size_t)(f0 + fl) * FEAT + c0 + c];
        }
        __syncthreads();
        for (int c = 0; c < 64; ++c) {
            float a[4], bb[4];
            for (int j = 0; j < 4; ++j) a[j] = As[c][tn * 4 + j];
            for (int i = 0; i < 4; ++i) bb[i] = Bs[c][tf * 4 + i];
            for (int j = 0; j < 4; ++j)
                for (int i = 0; i < 4; ++i)
                    acc[j][i] = __builtin_fmaf(a[j], bb[i], acc[j][i]);
        }
        __syncthreads();
    }
    for (int j = 0; j < 4; ++j) {
        const int n = n0 + tn * 4 + j;
        float4 v;
        v.x = acc[j][0] + bias[f0 + tf * 4 + 0];
        v.y = acc[j][1] + bias[f0 + tf * 4 + 1];
        v.z = acc[j][2] + bias[f0 + tf * 4 + 2];
        v.w = acc[j][3] + bias[f0 + tf * 4 + 3];
        *(float4*)(Ht + ((size_t)b * NPTS + n) * FEAT + f0 + tf * 4) = v;
    }
}

// ---------------- usage counts of each point column ----------------
__global__ __launch_bounds__(256) void count_kernel(const int* __restrict__ idx,
                                                    int* __restrict__ cnt) {
    const int e = blockIdx.x * 256 + threadIdx.x;  // [0, B*N*K)
    const int b = e >> 17;                         // N*K = 131072 per batch
    atomicAdd(&cnt[b * NPTS + idx[e]], 1);
}

// ---------------- count-weighted per-channel partial sums ----------------
__global__ __launch_bounds__(256) void stats_partial(const float* __restrict__ Ht,
                                                     const int* __restrict__ cnt,
                                                     float* __restrict__ part) {
    const int b = blockIdx.y;
    const int n0 = blockIdx.x * 256;
    const int f = threadIdx.x;
    float s = 0.f, s2 = 0.f;
    for (int nl = 0; nl < 256; ++nl) {
        const int n = n0 + nl;
        const float c = (float)cnt[b * NPTS + n];
        const float v = Ht[((size_t)b * NPTS + n) * FEAT + f];
        s += c * v;
        s2 += c * v * v;
    }
    const int blk = b * 16 + blockIdx.x;
    part[blk * 512 + f] = s;
    part[blk * 512 + 256 + f] = s2;
}

__global__ __launch_bounds__(256) void stats_final(const float* __restrict__ part,
                                                   const float* __restrict__ gamma,
                                                   const float* __restrict__ beta,
                                                   float* __restrict__ sc,
                                                   float* __restrict__ sh) {
    const int f = threadIdx.x;
    float s = 0.f, s2 = 0.f;
    for (int blk = 0; blk < 64; ++blk) {
        s += part[blk * 512 + f];
        s2 += part[blk * 512 + 256 + f];
    }
    const float inv = 1.0f / (float)(BATCH * NPTS * KNN);
    const float mean = s * inv;
    const float var = s2 * inv - mean * mean;
    const float scale = gamma[f] * rsqrtf(var + 1e-5f);
    sc[f] = scale;
    sh[f] = beta[f] - scale * mean;
}

// ---------------- gather + affine + relu + max over K ----------------
#define NT 32
__global__ __launch_bounds__(256) void out_kernel(const float* __restrict__ Ht,
                                                  const int* __restrict__ idx,
                                                  const float* __restrict__ sc,
                                                  const float* __restrict__ sh,
                                                  float* __restrict__ out) {
    __shared__ float tile[NT][FEAT + 1];
    const int b = blockIdx.y;
    const int n0 = blockIdx.x * NT;
    const int f = threadIdx.x;
    const float scale = sc[f];
    const float shift = sh[f];
    const float* Hb = Ht + (size_t)b * NPTS * FEAT;
    const int* ib = idx + (size_t)b * NPTS * KNN;
    for (int nl = 0; nl < NT; ++nl) {
        const int n = n0 + nl;
        float acc = -1e30f;
        for (int k = 0; k < KNN; ++k) {
            const int u = ib[k * NPTS + n];  // uniform -> scalar load
            const float v = Hb[(size_t)u * FEAT + f];
            acc = fmaxf(acc, __builtin_fmaf(v, scale, shift));
        }
        tile[nl][f] = fmaxf(acc, 0.0f);
    }
    __syncthreads();
    const int nl2 = threadIdx.x & (NT - 1);
    const int fbase = threadIdx.x >> 5;  // 0..7
    for (int ff = 0; ff < FEAT; ff += 8) {
        const int f2 = fbase + ff;
        out[((size_t)b * FEAT + f2) * NPTS + n0 + nl2] = tile[nl2][f2];
    }
}

extern "C" void kernel_launch(void* const* d_in, const int* in_sizes, int n_in,
                              void* d_out, int out_size, void* d_ws, size_t ws_size,
                              hipStream_t stream) {
    (void)in_sizes; (void)n_in; (void)out_size; (void)ws_size;
    const float* xyz   = (const float*)d_in[0];
    const float* feat  = (const float*)d_in[1];
    const float* W     = (const float*)d_in[2];
    const float* bias  = (const float*)d_in[3];
    const float* gamma = (const float*)d_in[4];
    const float* beta  = (const float*)d_in[5];
    float* out = (float*)d_out;
    char* ws = (char*)d_ws;
    int*   idx  = (int*)(ws + OFF_IDX);
    float* Ht   = (float*)(ws + OFF_HT);
    int*   cnt  = (int*)(ws + OFF_CNT);
    float* part = (float*)(ws + OFF_PART);
    float* sc   = (float*)(ws + OFF_SC);
    float* sh   = (float*)(ws + OFF_SH);

    hipMemsetAsync(cnt, 0, BATCH * NPTS * sizeof(int), stream);
    knn_kernel<<<dim3(NPTS, BATCH), 64, 0, stream>>>(xyz, idx);
    gemm_kernel<<<dim3(NPTS / 64, FEAT / 64, BATCH), 256, 0, stream>>>(feat, W, bias, Ht);
    count_kernel<<<dim3(BATCH * NPTS * KNN / 256), 256, 0, stream>>>(idx, cnt);
    stats_partial<<<dim3(NPTS / 256, BATCH), 256, 0, stream>>>(Ht, cnt, part);
    stats_final<<<1, 256, 0, stream>>>(part, gamma, beta, sc, sh);
    out_kernel<<<dim3(NPTS / NT, BATCH), 256, 0, stream>>>(Ht, idx, sc, sh, out);
}